// Round 7
// baseline (125.311 us; speedup 1.0000x reference)
//
#include <hip/hip_runtime.h>
#include <math.h>

constexpr int B = 32, S = 4096, H = 512;
constexpr int UDIM = 256;            // u_kernel block
constexpr int FDIM = 128;            // flash block: 2 waves of 64
constexpr int MAX_SPLIT = 128;       // blocks per batch row-range split
constexpr float LOG2E = 1.44269504088896340736f;
constexpr float DEFER_THR = 11.5415603f;   // 8 nats in log2 domain

typedef float f4 __attribute__((ext_vector_type(4)));

// ---------------------------------------------------------------------------
// Kernel 1: u[b,k] = (sum_h h_t[b,h] * W[h,k]) * log2(e)   (tiny: 32x512)
// ---------------------------------------------------------------------------
__global__ __launch_bounds__(UDIM) void u_kernel(const float* __restrict__ h_t,
                                                 const float* __restrict__ W,
                                                 float* __restrict__ u) {
    const int b = blockIdx.y;
    const int k = blockIdx.x * UDIM + threadIdx.x;
    __shared__ float hs[H];
    for (int i = threadIdx.x; i < H; i += UDIM) hs[i] = h_t[b * H + i];
    __syncthreads();
    float a0 = 0.f, a1 = 0.f, a2 = 0.f, a3 = 0.f;
#pragma unroll 8
    for (int h = 0; h < H; h += 4) {
        a0 = fmaf(hs[h],     W[(size_t)(h)     * H + k], a0);
        a1 = fmaf(hs[h + 1], W[(size_t)(h + 1) * H + k], a1);
        a2 = fmaf(hs[h + 2], W[(size_t)(h + 2) * H + k], a2);
        a3 = fmaf(hs[h + 3], W[(size_t)(h + 3) * H + k], a3);
    }
    u[b * H + k] = ((a0 + a1) + (a2 + a3)) * LOG2E;
}

// ---------------------------------------------------------------------------
// Kernel 2: streaming pass. 2 independent softmax STREAMS (A/B halves of the
// wave's row range) x 2 row-GROUPS (lane>>5) = 4 independent row-chains per
// iteration per wave. 32-lane groups: lane j=lane&31 covers cols k*128+j*4.
// Reduce = 5 shfl steps per row-pair; cross-group + cross-stream merges once
// at wave end. ctx loads PLAIN (L3 retention across replays), stores NT.
// ---------------------------------------------------------------------------
__global__ __launch_bounds__(FDIM) void flash_kernel(const float* __restrict__ ctx,
                                                     const float* __restrict__ u,
                                                     float* __restrict__ newbuf,
                                                     float* __restrict__ pacc,
                                                     float* __restrict__ pml,
                                                     int nsplit) {
    const int b     = blockIdx.y;
    const int split = blockIdx.x;
    const int w     = threadIdx.x >> 6;  // wave 0/1
    const int lane  = threadIdx.x & 63;
    const int g     = lane >> 5;         // row-group 0/1
    const int j     = lane & 31;         // column lane within group
    const int rpb   = S / nsplit;        // rows per block (32 @ nsplit=128)
    const int rpw   = rpb / 2;           // rows per wave (16)
    const int hrw   = rpw / 2;           // rows per stream (8)
    const int s0    = split * rpb + w * rpw;

    const f4* ub = (const f4*)(u + (size_t)b * H);
    f4 uf[4];
#pragma unroll
    for (int k = 0; k < 4; ++k) uf[k] = ub[j + 32 * k];

    const size_t baseA = (size_t)b * S + s0;        // stream A rows
    const size_t baseB = baseA + hrw;               // stream B rows

    float mA = -INFINITY, lA = 0.f;
    float mB = -INFINITY, lB = 0.f;
    f4 accA[4] = {{0,0,0,0},{0,0,0,0},{0,0,0,0},{0,0,0,0}};
    f4 accB[4] = {{0,0,0,0},{0,0,0,0},{0,0,0,0},{0,0,0,0}};

#pragma unroll
    for (int r = 0; r < hrw; r += 2) {
        const size_t rowA = baseA + r + g;
        const size_t rowB = baseB + r + g;
        const f4* cra = (const f4*)(ctx + rowA * H);
        const f4* crb = (const f4*)(ctx + rowB * H);
        f4 cA[4], cB[4];
#pragma unroll
        for (int k = 0; k < 4; ++k) cA[k] = cra[j + 32 * k];
#pragma unroll
        for (int k = 0; k < 4; ++k) cB[k] = crb[j + 32 * k];

        f4* oa = (f4*)(newbuf + rowA * H);
        f4* ob = (f4*)(newbuf + rowB * H);
#pragma unroll
        for (int k = 0; k < 4; ++k) {
            __builtin_nontemporal_store(cA[k], oa + j + 32 * k);
            __builtin_nontemporal_store(cB[k], ob + j + 32 * k);
        }

        float dA = cA[0].x * uf[0].x, dB = cB[0].x * uf[0].x;
        dA = fmaf(cA[0].y, uf[0].y, dA); dB = fmaf(cB[0].y, uf[0].y, dB);
        dA = fmaf(cA[0].z, uf[0].z, dA); dB = fmaf(cB[0].z, uf[0].z, dB);
        dA = fmaf(cA[0].w, uf[0].w, dA); dB = fmaf(cB[0].w, uf[0].w, dB);
#pragma unroll
        for (int k = 1; k < 4; ++k) {
            dA = fmaf(cA[k].x, uf[k].x, dA); dB = fmaf(cB[k].x, uf[k].x, dB);
            dA = fmaf(cA[k].y, uf[k].y, dA); dB = fmaf(cB[k].y, uf[k].y, dB);
            dA = fmaf(cA[k].z, uf[k].z, dA); dB = fmaf(cB[k].z, uf[k].z, dB);
            dA = fmaf(cA[k].w, uf[k].w, dA); dB = fmaf(cB[k].w, uf[k].w, dB);
        }
        // reduce within each 32-lane group (bit 5 untouched), chains interleaved
#pragma unroll
        for (int off = 16; off >= 1; off >>= 1) {
            dA += __shfl_xor(dA, off);
            dB += __shfl_xor(dB, off);
        }

        if (dA > mA + DEFER_THR) {              // group-uniform, rare
            const float sc = exp2f(mA - dA);    // first time: exp2(-inf)=0
#pragma unroll
            for (int k = 0; k < 4; ++k) accA[k] *= sc;
            lA *= sc; mA = dA;
        }
        if (dB > mB + DEFER_THR) {
            const float sc = exp2f(mB - dB);
#pragma unroll
            for (int k = 0; k < 4; ++k) accB[k] *= sc;
            lB *= sc; mB = dB;
        }
        const float pA = exp2f(dA - mA);        // bounded by e^8
        const float pB = exp2f(dB - mB);
#pragma unroll
        for (int k = 0; k < 4; ++k) {
            accA[k] += pA * cA[k];
            accB[k] += pB * cB[k];
        }
        lA += pA; lB += pB;
    }

    // ---- merge the two 32-lane groups inside each stream ----
    const float moA = __shfl_xor(mA, 32), loA = __shfl_xor(lA, 32);
    const float moB = __shfl_xor(mB, 32), loB = __shfl_xor(lB, 32);
    const float MA = fmaxf(mA, moA), MB = fmaxf(mB, moB);
    const float esA = exp2f(mA - MA), eoA = exp2f(moA - MA);
    const float esB = exp2f(mB - MB), eoB = exp2f(moB - MB);
    const float lwA = esA * lA + eoA * loA;
    const float lwB = esB * lB + eoB * loB;
#pragma unroll
    for (int k = 0; k < 4; ++k) {
        f4 oA, oB;
        oA.x = __shfl_xor(accA[k].x, 32); oB.x = __shfl_xor(accB[k].x, 32);
        oA.y = __shfl_xor(accA[k].y, 32); oB.y = __shfl_xor(accB[k].y, 32);
        oA.z = __shfl_xor(accA[k].z, 32); oB.z = __shfl_xor(accB[k].z, 32);
        oA.w = __shfl_xor(accA[k].w, 32); oB.w = __shfl_xor(accB[k].w, 32);
        accA[k] = esA * accA[k] + eoA * oA;
        accB[k] = esB * accB[k] + eoB * oB;
    }
    // ---- merge streams A/B in-register (all lanes consistent) ----
    const float Mw = fmaxf(MA, MB);
    const float eA = exp2f(MA - Mw), eB = exp2f(MB - Mw);
    const float lw = eA * lwA + eB * lwB;
    f4 am[4];
#pragma unroll
    for (int k = 0; k < 4; ++k) am[k] = eA * accA[k] + eB * accB[k];

    // ---- block-level reduce of 2 wave partials via LDS ----
    __shared__ float lacc[2][H];
    __shared__ float lml[2][2];
    if (g == 0) {
        f4* dst = (f4*)&lacc[w][0];
#pragma unroll
        for (int k = 0; k < 4; ++k) dst[j + 32 * k] = am[k];
        if (j == 0) { lml[w][0] = Mw; lml[w][1] = lw; }
    }
    __syncthreads();

    const float m0 = lml[0][0], m1 = lml[1][0];
    const float Mb = fmaxf(m0, m1);
    const float e0 = exp2f(m0 - Mb), e1 = exp2f(m1 - Mb);

    const int t    = threadIdx.x;                 // 128 threads x f4 = 512
    const int pidx = b * nsplit + split;
    f4* pa = (f4*)(pacc + (size_t)pidx * H);
    const f4* l0 = (const f4*)&lacc[0][0];
    const f4* l1 = (const f4*)&lacc[1][0];
    pa[t] = e0 * l0[t] + e1 * l1[t];
    if (t == 0) {
        const float L = e0 * lml[0][1] + e1 * lml[1][1];
        pml[2 * pidx] = Mb; pml[2 * pidx + 1] = L;
    }
}

// ---------------------------------------------------------------------------
// Kernel 3: combine per-block partials -> cntx[b,:]; also writes the cyclic-
// buffer row: newbuf[b,pos,:] = h_t[b,:] (ordered after flash).  grid=(B,2).
// ---------------------------------------------------------------------------
__global__ __launch_bounds__(256) void combine_kernel(const float* __restrict__ pacc,
                                                      const float* __restrict__ pml,
                                                      const float* __restrict__ h_t,
                                                      const int* __restrict__ posp,
                                                      float* __restrict__ newbuf,
                                                      float* __restrict__ cntx,
                                                      int nsplit) {
    const int b    = blockIdx.x;
    const int half = blockIdx.y;
    const int t    = threadIdx.x;
    const int col  = half * 256 + t;

    int pos = posp[0] % S; if (pos < 0) pos += S;
    newbuf[((size_t)b * S + pos) * H + col] = h_t[b * H + col];

    __shared__ float lm[MAX_SPLIT], ll[MAX_SPLIT];
    for (int p = t; p < nsplit; p += 256) {
        lm[p] = pml[2 * (b * nsplit + p)];
        ll[p] = pml[2 * (b * nsplit + p) + 1];
    }
    __syncthreads();

    float M = -INFINITY;
    for (int p = 0; p < nsplit; ++p) M = fmaxf(M, lm[p]);

    float acc = 0.f, L = 0.f;
#pragma unroll 4
    for (int p = 0; p < nsplit; ++p) {
        const float e = exp2f(lm[p] - M);
        L   = fmaf(e, ll[p], L);
        acc = fmaf(e, pacc[(size_t)(b * nsplit + p) * H + col], acc);
    }
    cntx[b * H + col] = acc / L;
}

// ---------------------------------------------------------------------------
extern "C" void kernel_launch(void* const* d_in, const int* in_sizes, int n_in,
                              void* d_out, int out_size, void* d_ws, size_t ws_size,
                              hipStream_t stream) {
    const float* h_t = (const float*)d_in[0];
    const float* ctx = (const float*)d_in[1];
    const float* W   = (const float*)d_in[2];
    const int*   pos = (const int*)d_in[3];

    float* out    = (float*)d_out;
    float* cntx   = out;                     // [B,H]
    float* newbuf = out + (size_t)B * H;     // [B,S,H]

    // workspace layout: u [B*H] | pacc [B*nsplit*H] | pml [B*nsplit*2]
    char*  ws = (char*)d_ws;
    float* u  = (float*)ws;
    const size_t u_bytes = (size_t)B * H * sizeof(float);

    int nsplit = MAX_SPLIT;
    while (nsplit > 1) {
        const size_t need = u_bytes
                          + (size_t)B * nsplit * H * sizeof(float)
                          + (size_t)B * nsplit * 2 * sizeof(float);
        if (need <= ws_size) break;
        nsplit >>= 1;
    }
    float* pacc = (float*)(ws + u_bytes);
    float* pml  = pacc + (size_t)B * nsplit * H;

    u_kernel<<<dim3(H / UDIM, B), UDIM, 0, stream>>>(h_t, W, u);
    flash_kernel<<<dim3(nsplit, B), FDIM, 0, stream>>>(ctx, u, newbuf,
                                                       pacc, pml, nsplit);
    combine_kernel<<<dim3(B, 2), 256, 0, stream>>>(pacc, pml, h_t, pos,
                                                   newbuf, cntx, nsplit);
}